// Round 21
// baseline (115.759 us; speedup 1.0000x reference)
//
#include <hip/hip_runtime.h>

typedef __bf16 bf16;
typedef __attribute__((ext_vector_type(8))) __bf16 bf16x8;
typedef __attribute__((ext_vector_type(4))) float f32x4;
typedef __attribute__((ext_vector_type(4))) short s16x4;
typedef __attribute__((ext_vector_type(4))) unsigned u32x4;

#define SEQ 2048
#define DM 1024
#define NH 16
#define HD 64
// SCALE * log2(e) folded into q at projection epilogue; softmax uses exp2.
#define QSCALE 0.1803368801111204f

static __device__ __forceinline__ void gl_lds16(const bf16* g, bf16* l) {
  __builtin_amdgcn_global_load_lds(
      (const __attribute__((address_space(1))) void*)g,
      (__attribute__((address_space(3))) void*)l, 16, 0, 0);
}

static __device__ __forceinline__ f32x4 mfma16(bf16x8 a, bf16x8 b, f32x4 c) {
  return __builtin_amdgcn_mfma_f32_16x16x32_bf16(a, b, c, 0, 0, 0);
}

static __device__ __forceinline__ unsigned cvt_pk_bf16(float lo, float hi) {
  unsigned r;
  asm("v_cvt_pk_bf16_f32 %0, %1, %2" : "=v"(r) : "v"(lo), "v"(hi));
  return r;
}

static __device__ __forceinline__ float vmax4(f32x4 v) {
  return fmaxf(fmaxf(v[0], v[1]), fmaxf(v[2], v[3]));
}

// Fused prep: cast x (1048576 f32x4) + wq/wk/wv/wo (4x262144 f32x4, contiguous
// dst = wqkv||wo) + RoPE cos/sin table (65536 float2). One dispatch.
__global__ __launch_bounds__(256)
void prep_k(const float* __restrict__ x, const float* __restrict__ wq,
            const float* __restrict__ wk, const float* __restrict__ wv,
            const float* __restrict__ wo, bf16* __restrict__ xb,
            bf16* __restrict__ wb, float* __restrict__ tab) {
  int i = blockIdx.x * 256 + threadIdx.x;
  if (i < 2097152) {
    const float* src;
    bf16* dst;
    int j;
    if (i < 1048576) {
      src = x; dst = xb; j = i;
    } else {
      j = i - 1048576;
      int seg = j >> 18;
      src = (seg == 0) ? wq : (seg == 1) ? wk : (seg == 2) ? wv : wo;
      dst = wb;
      src -= (size_t)seg << 20;  // undo j's segment offset (j*4 spans all 4)
    }
    f32x4 v = ((const f32x4*)src)[j];
    s16x4 o;
#pragma unroll
    for (int q = 0; q < 4; ++q) o[q] = __builtin_bit_cast(short, (bf16)v[q]);
    ((s16x4*)dst)[j] = o;
  } else {
    int idx = i - 2097152;  // 0..65535
    int s = idx >> 5, j = idx & 31;
    float inv = powf(10000.0f, -(float)j * (1.0f / 32.0f));
    float f = (float)s * inv;
    tab[idx * 2] = cosf(f);
    tab[idx * 2 + 1] = sinf(f);
  }
}

// Fused QKV projection: A = x [4096x1024] bf16, B = wqkv [3072x1024] bf16.
// n in [0,1024): q -> RoPE + QSCALE -> qh[b][h][s][64]
// n in [1024,2048): k -> RoPE -> kh[b][h][s][64]
// n in [2048,3072): v -> vt[b][h][d][s]
// 2-D XCD chunking (R18). T4 counted-vmcnt pipeline, now 3-DEEP (R19 proved
// 2-deep counted > drain; kernel is fetch-latency bound at 1.2 TB/s, so
// deeper prefetch = more memory-level parallelism). LDS 48 KB = 3 blocks/CU,
// matching the 768-block grid exactly. Steady state: vmcnt(8) keeps TWO full
// tiles (8 loads) in flight across the barrier; tail peels 4 -> 0.
__global__ __launch_bounds__(256)
void gemm_qkv(const bf16* __restrict__ A, const bf16* __restrict__ B,
              bf16* __restrict__ qh, bf16* __restrict__ kh, bf16* __restrict__ vt,
              const float2* __restrict__ tab) {
  const int K = 1024;
  __shared__ __attribute__((aligned(16))) bf16 As[3][128 * 32];
  __shared__ __attribute__((aligned(16))) bf16 Bs[3][128 * 32];
  const int t = threadIdx.x;
  const int wv = t >> 6, ln = t & 63, lr = ln & 15, lg = ln >> 4;
  const int wr = wv >> 1, wc = wv & 1;
  const int l_hw = blockIdx.x + 24 * blockIdx.y;  // hw dispatch order, 0..767
  const int xcd = l_hw & 7, i = l_hw >> 3;        // i in 0..95
  const int mi = i / 12, ni = i % 12;             // n-fastest within chunk
  const int m0 = ((xcd >> 1) * 8 + mi) * 128;     // chunk grid: 4 along m
  const int n0 = ((xcd & 1) * 12 + ni) * 128;     //             2 along n
  const int srow = t >> 2, sslot = t & 3;
  const int seg = n0 >> 10;                       // 0=q 1=k 2=v (uniform per block)
  const int hh = ((n0 & 1023) + wc * 64) >> 6;    // head (uniform per wave)

  f32x4 acc[4][4] = {};

  auto STAGE = [&](int buf, int kt) {  // 4 VMEM instructions per wave
#pragma unroll
    for (int c = 0; c < 2; ++c) {
      int row = srow + (c << 6);
      int lsl = sslot ^ (row & 3);
      gl_lds16(A + (size_t)(m0 + row) * K + kt + lsl * 8, &As[buf][0] + c * 2048 + wv * 512);
      gl_lds16(B + (size_t)(n0 + row) * K + kt + lsl * 8, &Bs[buf][0] + c * 2048 + wv * 512);
    }
  };

  auto COMPUTE = [&](int buf) {
    bf16x8 af[4], bfr[4];
#pragma unroll
    for (int i2 = 0; i2 < 4; ++i2) {
      int ra = wr * 64 + i2 * 16 + lr;
      af[i2] = *(const bf16x8*)(&As[buf][0] + ra * 32 + ((lg ^ (ra & 3)) << 3));
      int rb = wc * 64 + i2 * 16 + lr;
      bfr[i2] = *(const bf16x8*)(&Bs[buf][0] + rb * 32 + ((lg ^ (rb & 3)) << 3));
    }
#pragma unroll
    for (int i2 = 0; i2 < 4; ++i2)
#pragma unroll
      for (int j = 0; j < 4; ++j)
        acc[i2][j] = mfma16(af[i2], bfr[j], acc[i2][j]);
  };

  STAGE(0, 0);
  STAGE(1, 32);
  STAGE(2, 64);
  int buf = 0;
  for (int tt = 0; tt < 32; ++tt) {
    if (tt < 30)
      asm volatile("s_waitcnt vmcnt(8)" ::: "memory");   // tiles tt+1, tt+2 in flight
    else if (tt == 30)
      asm volatile("s_waitcnt vmcnt(4)" ::: "memory");   // tile 31 in flight
    else
      asm volatile("s_waitcnt vmcnt(0)" ::: "memory");   // last tile
    __builtin_amdgcn_s_barrier();
    COMPUTE(buf);
    asm volatile("s_waitcnt lgkmcnt(0)" ::: "memory");   // reads of buf done
    __builtin_amdgcn_s_barrier();
    if (tt + 3 < 32) STAGE(buf, (tt + 3) * 32);
    buf = (buf == 2) ? 0 : buf + 1;
  }

#pragma unroll
  for (int i2 = 0; i2 < 4; ++i2) {
    int row0 = m0 + wr * 64 + i2 * 16 + lg * 4;
    int bb = row0 >> 11, s0r = row0 & (SEQ - 1);
    if (seg < 2) {
      bf16* dst = (seg == 0) ? qh : kh;
      float scl = (seg == 0) ? QSCALE : 1.0f;
      size_t base = ((size_t)(bb * NH + hh) * SEQ + s0r) * HD;
#pragma unroll
      for (int j = 0; j < 2; ++j) {
        int dlo = j * 16 + lr;  // 0..31
#pragma unroll
        for (int r = 0; r < 4; ++r) {
          float2 cs = tab[(size_t)(s0r + r) * 32 + dlo];
          float a = acc[i2][j][r], b2 = acc[i2][j + 2][r];
          float na = (a * cs.x - b2 * cs.y) * scl;
          float nb = (b2 * cs.x + a * cs.y) * scl;
          dst[base + (size_t)r * HD + dlo] = (bf16)na;
          dst[base + (size_t)r * HD + dlo + 32] = (bf16)nb;
        }
      }
    } else {
#pragma unroll
      for (int j = 0; j < 4; ++j) {
        int d = j * 16 + lr;
        s16x4 pk;
#pragma unroll
        for (int r = 0; r < 4; ++r) pk[r] = __builtin_bit_cast(short, (bf16)acc[i2][j][r]);
        *(s16x4*)(vt + ((size_t)(bb * NH + hh) * HD + d) * SEQ + s0r) = pk;
      }
    }
  }
}

// C = A(MxK) * B(NxK)^T, f32 out (final projection). T1 XCD-chunked remap +
// 3-deep counted-vmcnt pipeline (same as gemm_qkv).
__global__ __launch_bounds__(256)
void gemm_bt_f32(const bf16* __restrict__ A, const bf16* __restrict__ B,
                 float* __restrict__ C, int M, int N, int K) {
  __shared__ __attribute__((aligned(16))) bf16 As[3][128 * 32];
  __shared__ __attribute__((aligned(16))) bf16 Bs[3][128 * 32];
  const int t = threadIdx.x;
  const int wv = t >> 6, ln = t & 63, lr = ln & 15, lg = ln >> 4;
  const int wr = wv >> 1, wc = wv & 1;
  const int l_hw = blockIdx.x + 8 * blockIdx.y;      // hw dispatch order
  const int lid = (l_hw & 7) * 32 + (l_hw >> 3);     // bijective (256 % 8 == 0)
  const int m0 = (lid >> 3) * 128, n0 = (lid & 7) * 128;
  const int srow = t >> 2, sslot = t & 3;

  f32x4 acc[4][4] = {};

  auto STAGE = [&](int buf, int kt) {
#pragma unroll
    for (int c = 0; c < 2; ++c) {
      int row = srow + (c << 6);
      int lsl = sslot ^ (row & 3);
      gl_lds16(A + (size_t)(m0 + row) * K + kt + lsl * 8, &As[buf][0] + c * 2048 + wv * 512);
      gl_lds16(B + (size_t)(n0 + row) * K + kt + lsl * 8, &Bs[buf][0] + c * 2048 + wv * 512);
    }
  };

  auto COMPUTE = [&](int buf) {
    bf16x8 af[4], bfr[4];
#pragma unroll
    for (int i = 0; i < 4; ++i) {
      int ra = wr * 64 + i * 16 + lr;
      af[i] = *(const bf16x8*)(&As[buf][0] + ra * 32 + ((lg ^ (ra & 3)) << 3));
      int rb = wc * 64 + i * 16 + lr;
      bfr[i] = *(const bf16x8*)(&Bs[buf][0] + rb * 32 + ((lg ^ (rb & 3)) << 3));
    }
#pragma unroll
    for (int i = 0; i < 4; ++i)
#pragma unroll
      for (int j = 0; j < 4; ++j)
        acc[i][j] = mfma16(af[i], bfr[j], acc[i][j]);
  };

  STAGE(0, 0);
  STAGE(1, 32);
  STAGE(2, 64);
  int buf = 0;
  for (int tt = 0; tt < 32; ++tt) {
    if (tt < 30)
      asm volatile("s_waitcnt vmcnt(8)" ::: "memory");
    else if (tt == 30)
      asm volatile("s_waitcnt vmcnt(4)" ::: "memory");
    else
      asm volatile("s_waitcnt vmcnt(0)" ::: "memory");
    __builtin_amdgcn_s_barrier();
    COMPUTE(buf);
    asm volatile("s_waitcnt lgkmcnt(0)" ::: "memory");
    __builtin_amdgcn_s_barrier();
    if (tt + 3 < 32) STAGE(buf, (tt + 3) * 32);
    buf = (buf == 2) ? 0 : buf + 1;
  }

#pragma unroll
  for (int i = 0; i < 4; ++i) {
    int row0 = m0 + wr * 64 + i * 16 + lg * 4;
#pragma unroll
    for (int j = 0; j < 4; ++j) {
      int col = n0 + wc * 64 + j * 16 + lr;
#pragma unroll
      for (int r = 0; r < 4; ++r)
        C[(size_t)(row0 + r) * N + col] = acc[i][j][r];
    }
  }
}

// ---------------- Flash attention: R7 body + T4 counted-vmcnt (R20 form) ----
// 1024 blocks x 256 thr (4 waves). Block = (bh, qt); LDS 40 KB -> 4 blocks/CU.
// Proven plateau config: swapped MFMAs, lane-local softmax, P via swizzled
// LDS, T13 defer-max, counted 2-deep staging pipeline.
template <bool MASKED>
static __device__ __forceinline__ void attn_tile_lds(
    const bf16* Ksb, const bf16* Vsb, unsigned* plw,
    const bf16x8* qf, f32x4* acc, float& m_run, float& l_run,
    int lr, int lg, int qrow, int s0) {
  // ---- QK^T (swapped: A=K from LDS, B=q regs) ----
  f32x4 sc[4] = {};
#pragma unroll
  for (int fi = 0; fi < 4; ++fi) {
    int row = fi * 16 + lr;
    int sw = row & 7;
    bf16x8 k0 = *(const bf16x8*)(Ksb + row * 64 + ((lg ^ sw) << 3));
    bf16x8 k1 = *(const bf16x8*)(Ksb + row * 64 + (((4 + lg) ^ sw) << 3));
    sc[fi] = mfma16(k0, qf[0], sc[fi]);
    sc[fi] = mfma16(k1, qf[1], sc[fi]);
  }
  // ---- mask (diagonal tile only) ----
  if (MASKED) {
#pragma unroll
    for (int fi = 0; fi < 4; ++fi)
#pragma unroll
      for (int r = 0; r < 4; ++r) {
        int kv = s0 + fi * 16 + lg * 4 + r;
        sc[fi][r] = (kv <= qrow) ? sc[fi][r] : -3e38f;
      }
  }
  // ---- lane-local softmax (q = lr fixed per lane) ----
  float mx = fmaxf(fmaxf(vmax4(sc[0]), vmax4(sc[1])),
                   fmaxf(vmax4(sc[2]), vmax4(sc[3])));
  mx = fmaxf(mx, __shfl_xor(mx, 16));
  mx = fmaxf(mx, __shfl_xor(mx, 32));
  // T13 defer-max: only rescale when some q-row exceeds its running max.
  if (!__all(mx <= m_run)) {
    float mn = fmaxf(m_run, mx);
    float alpha = __builtin_amdgcn_exp2f(m_run - mn);
    m_run = mn;
    l_run *= alpha;
#pragma unroll
    for (int d0 = 0; d0 < 4; ++d0)
#pragma unroll
      for (int r = 0; r < 4; ++r) acc[d0][r] *= alpha;
  }
  float pf[4][4], sm = 0.0f;
#pragma unroll
  for (int fi = 0; fi < 4; ++fi)
#pragma unroll
    for (int r = 0; r < 4; ++r) {
      pf[fi][r] = __builtin_amdgcn_exp2f(sc[fi][r] - m_run);
      sm += pf[fi][r];
    }
  sm += __shfl_xor(sm, 16);
  sm += __shfl_xor(sm, 32);
  l_run += sm;

  // ---- P: (kv = fi*16+lg*4+r, q = lr) -> q-major B-fragments via LDS ----
  const int sw2 = (lr & 7) << 2;
#pragma unroll
  for (int fi = 0; fi < 4; ++fi)
#pragma unroll
    for (int hh = 0; hh < 2; ++hh)
      plw[lr * 32 + ((fi * 8 + lg * 2 + hh) ^ sw2)] =
          cvt_pk_bf16(pf[fi][2 * hh], pf[fi][2 * hh + 1]);
  asm volatile("s_waitcnt lgkmcnt(0)" ::: "memory");
  __builtin_amdgcn_sched_barrier(0);
#pragma unroll
  for (int kc = 0; kc < 2; ++kc) {
    u32x4 praw = *(const u32x4*)(plw + lr * 32 + ((kc * 16 + lg * 4) ^ sw2));
    bf16x8 pb = __builtin_bit_cast(bf16x8, praw);
#pragma unroll
    for (int d0 = 0; d0 < 4; ++d0) {
      int row = d0 * 16 + lr;
      int sw = row & 7;
      bf16x8 vf = *(const bf16x8*)(Vsb + row * 64 + (((kc * 4 + lg) ^ sw) << 3));
      acc[d0] = mfma16(vf, pb, acc[d0]);
    }
  }
  // keep later LDS writes from hoisting above this tile's reads
  asm volatile("" ::: "memory");
}

__global__ __launch_bounds__(256, 4)
void attn_k(const bf16* __restrict__ qh, const bf16* __restrict__ kh,
            const bf16* __restrict__ vt, bf16* __restrict__ ao) {
  __shared__ __attribute__((aligned(16))) bf16 Ks[2][64 * 64];    // 16 KB
  __shared__ __attribute__((aligned(16))) bf16 Vs[2][64 * 64];    // 16 KB
  __shared__ __attribute__((aligned(16))) unsigned plds[4][512];  // 8 KB

  const int t = threadIdx.x, wv = t >> 6, ln = t & 63, lr = ln & 15, lg = ln >> 4;
  // LPT + XCD-grouped: xcd = bid&7 owns 4 bh; qt descending within each XCD.
  const int bid = blockIdx.x;            // 1024 blocks
  const int xcd = bid & 7, g = bid >> 3; // g in 0..127
  const int bh = xcd * 4 + (g & 3);
  const int qt = 31 - (g >> 2);
  const int b = bh >> 4, h = bh & 15;

  const bf16* qp = qh + (size_t)bh * SEQ * HD;
  const bf16* kp = kh + (size_t)bh * SEQ * HD;
  const bf16* vp = vt + (size_t)bh * HD * SEQ;
  unsigned* plw = &plds[wv][0];

  const int qrow = qt * 64 + wv * 16 + lr;

  bf16x8 qf[2];
  qf[0] = *(const bf16x8*)(qp + (size_t)qrow * HD + lg * 8);
  qf[1] = *(const bf16x8*)(qp + (size_t)qrow * HD + 32 + lg * 8);

  f32x4 acc[4] = {};
  float m_run = -3e38f, l_run = 0.0f;

  const int nt = qt + 1;

  auto STAGE = [&](int buf, int tt) {  // 4 VMEM instructions per wave
    int s0 = tt * 64;
#pragma unroll
    for (int c = 0; c < 2; ++c) {
      int rA = wv * 16 + c * 8;            // wave-uniform 8-row chunk base
      int row = rA + (ln >> 3);
      int sl = (ln & 7) ^ (row & 7);       // pre-swizzled global source
      gl_lds16(kp + (size_t)(s0 + row) * HD + (sl << 3), &Ks[buf][rA * 64]);
      gl_lds16(vp + (size_t)row * SEQ + s0 + (sl << 3), &Vs[buf][rA * 64]);
    }
  };

  STAGE(0, 0);
  if (nt > 1) STAGE(1, 1);

  int cur = 0;
  for (int tt = 0; tt < nt; ++tt) {
    if (tt + 1 < nt)
      asm volatile("s_waitcnt vmcnt(4)" ::: "memory");  // tile tt landed; tt+1 in flight
    else
      asm volatile("s_waitcnt vmcnt(0)" ::: "memory");  // last tile: nothing beyond
    __builtin_amdgcn_s_barrier();
    if (tt == qt)
      attn_tile_lds<true>(&Ks[cur][0], &Vs[cur][0], plw, qf, acc, m_run, l_run,
                          lr, lg, qrow, tt * 64);
    else
      attn_tile_lds<false>(&Ks[cur][0], &Vs[cur][0], plw, qf, acc, m_run, l_run,
                           lr, lg, qrow, tt * 64);
    asm volatile("s_waitcnt lgkmcnt(0)" ::: "memory");  // all reads of buf cur done
    __builtin_amdgcn_s_barrier();
    if (tt + 2 < nt) STAGE(cur, tt + 2);
    cur ^= 1;
  }

  // epilogue: acc^T (d = d0*16+lg*4+r, q = lr) -> ao[b][s=qrow][h*64+d]
  float invl = 1.0f / l_run;
  bf16* aop = ao + ((size_t)b * SEQ + qrow) * DM + h * HD;
#pragma unroll
  for (int d0 = 0; d0 < 4; ++d0) {
    unsigned lo = cvt_pk_bf16(acc[d0][0] * invl, acc[d0][1] * invl);
    unsigned hi = cvt_pk_bf16(acc[d0][2] * invl, acc[d0][3] * invl);
    uint2 pk; pk.x = lo; pk.y = hi;
    *(uint2*)(aop + d0 * 16 + lg * 4) = pk;
  }
}

extern "C" void kernel_launch(void* const* d_in, const int* in_sizes, int n_in,
                              void* d_out, int out_size, void* d_ws, size_t ws_size,
                              hipStream_t stream) {
  const float* x = (const float*)d_in[0];
  const float* wq = (const float*)d_in[1];
  const float* wk = (const float*)d_in[2];
  const float* wv = (const float*)d_in[3];
  const float* wo = (const float*)d_in[4];
  // d_in[5] = attention_mask: known causal tril, handled analytically.

  char* ws = (char*)d_ws;
  const size_t MB = 1ull << 20;
  bf16* xb    = (bf16*)ws;              // 8 MB (reused as attn-out once x is dead)
  bf16* wqkvb = (bf16*)(ws + 8 * MB);   // 6 MB [3072][1024]
  bf16* wob   = (bf16*)(ws + 14 * MB);  // 2 MB
  bf16* qhb   = (bf16*)(ws + 16 * MB);  // 8 MB [b][h][s][64]
  bf16* khb   = (bf16*)(ws + 24 * MB);  // 8 MB [b][h][s][64]
  bf16* vtb   = (bf16*)(ws + 32 * MB);  // 8 MB [b][h][d][s]
  float* tab  = (float*)(ws + 40 * MB); // 512 KB float2[2048][32]
  bf16* aob = xb;

  prep_k<<<8448, 256, 0, stream>>>(x, wq, wk, wv, wo, xb, wqkvb, tab);

  gemm_qkv<<<dim3(24, 32), 256, 0, stream>>>(xb, wqkvb, qhb, khb, vtb, (const float2*)tab);

  attn_k<<<1024, 256, 0, stream>>>(qhb, khb, vtb, aob);

  gemm_bt_f32<<<dim3(8, 32), 256, 0, stream>>>(aob, wob, (float*)d_out, 4096, 1024, 1024);
}

// Round 22
// 113.500 us; speedup vs baseline: 1.0199x; 1.0199x over previous
//
#include <hip/hip_runtime.h>

typedef __bf16 bf16;
typedef __attribute__((ext_vector_type(8))) __bf16 bf16x8;
typedef __attribute__((ext_vector_type(4))) float f32x4;
typedef __attribute__((ext_vector_type(4))) short s16x4;
typedef __attribute__((ext_vector_type(4))) unsigned u32x4;

#define SEQ 2048
#define DM 1024
#define NH 16
#define HD 64
// SCALE * log2(e) folded into q at projection epilogue; softmax uses exp2.
#define QSCALE 0.1803368801111204f

static __device__ __forceinline__ void gl_lds16(const bf16* g, bf16* l) {
  __builtin_amdgcn_global_load_lds(
      (const __attribute__((address_space(1))) void*)g,
      (__attribute__((address_space(3))) void*)l, 16, 0, 0);
}

static __device__ __forceinline__ f32x4 mfma16(bf16x8 a, bf16x8 b, f32x4 c) {
  return __builtin_amdgcn_mfma_f32_16x16x32_bf16(a, b, c, 0, 0, 0);
}

static __device__ __forceinline__ unsigned cvt_pk_bf16(float lo, float hi) {
  unsigned r;
  asm("v_cvt_pk_bf16_f32 %0, %1, %2" : "=v"(r) : "v"(lo), "v"(hi));
  return r;
}

static __device__ __forceinline__ float vmax4(f32x4 v) {
  return fmaxf(fmaxf(v[0], v[1]), fmaxf(v[2], v[3]));
}

// Fused prep: cast x (1048576 f32x4) + wq/wk/wv/wo (4x262144 f32x4, contiguous
// dst = wqkv||wo) + RoPE cos/sin table (65536 float2). One dispatch.
__global__ __launch_bounds__(256)
void prep_k(const float* __restrict__ x, const float* __restrict__ wq,
            const float* __restrict__ wk, const float* __restrict__ wv,
            const float* __restrict__ wo, bf16* __restrict__ xb,
            bf16* __restrict__ wb, float* __restrict__ tab) {
  int i = blockIdx.x * 256 + threadIdx.x;
  if (i < 2097152) {
    const float* src;
    bf16* dst;
    int j;
    if (i < 1048576) {
      src = x; dst = xb; j = i;
    } else {
      j = i - 1048576;
      int seg = j >> 18;
      src = (seg == 0) ? wq : (seg == 1) ? wk : (seg == 2) ? wv : wo;
      dst = wb;
      src -= (size_t)seg << 20;  // undo j's segment offset (j*4 spans all 4)
    }
    f32x4 v = ((const f32x4*)src)[j];
    s16x4 o;
#pragma unroll
    for (int q = 0; q < 4; ++q) o[q] = __builtin_bit_cast(short, (bf16)v[q]);
    ((s16x4*)dst)[j] = o;
  } else {
    int idx = i - 2097152;  // 0..65535
    int s = idx >> 5, j = idx & 31;
    float inv = powf(10000.0f, -(float)j * (1.0f / 32.0f));
    float f = (float)s * inv;
    tab[idx * 2] = cosf(f);
    tab[idx * 2 + 1] = sinf(f);
  }
}

// Fused QKV projection: A = x [4096x1024] bf16, B = wqkv [3072x1024] bf16.
// n in [0,1024): q -> RoPE + QSCALE -> qh[b][h][s][64]
// n in [1024,2048): k -> RoPE -> kh[b][h][s][64]
// n in [2048,3072): v -> vt[b][h][d][s]
// 2-D XCD chunking (R18). T4 counted-vmcnt double-buffer pipeline (R19 WIN;
// R21 showed 3-deep is slightly worse -> 2-deep is the measured optimum).
__global__ __launch_bounds__(256)
void gemm_qkv(const bf16* __restrict__ A, const bf16* __restrict__ B,
              bf16* __restrict__ qh, bf16* __restrict__ kh, bf16* __restrict__ vt,
              const float2* __restrict__ tab) {
  const int K = 1024;
  __shared__ __attribute__((aligned(16))) bf16 As[2][128 * 32];
  __shared__ __attribute__((aligned(16))) bf16 Bs[2][128 * 32];
  const int t = threadIdx.x;
  const int wv = t >> 6, ln = t & 63, lr = ln & 15, lg = ln >> 4;
  const int wr = wv >> 1, wc = wv & 1;
  const int l_hw = blockIdx.x + 24 * blockIdx.y;  // hw dispatch order, 0..767
  const int xcd = l_hw & 7, i = l_hw >> 3;        // i in 0..95
  const int mi = i / 12, ni = i % 12;             // n-fastest within chunk
  const int m0 = ((xcd >> 1) * 8 + mi) * 128;     // chunk grid: 4 along m
  const int n0 = ((xcd & 1) * 12 + ni) * 128;     //             2 along n
  const int srow = t >> 2, sslot = t & 3;
  const int seg = n0 >> 10;                       // 0=q 1=k 2=v (uniform per block)
  const int hh = ((n0 & 1023) + wc * 64) >> 6;    // head (uniform per wave)

  f32x4 acc[4][4] = {};

  auto STAGE = [&](int buf, int kt) {  // 4 VMEM instructions per wave
#pragma unroll
    for (int c = 0; c < 2; ++c) {
      int row = srow + (c << 6);
      int lsl = sslot ^ (row & 3);
      gl_lds16(A + (size_t)(m0 + row) * K + kt + lsl * 8, &As[buf][0] + c * 2048 + wv * 512);
      gl_lds16(B + (size_t)(n0 + row) * K + kt + lsl * 8, &Bs[buf][0] + c * 2048 + wv * 512);
    }
  };

  auto COMPUTE = [&](int buf) {
    bf16x8 af[4], bfr[4];
#pragma unroll
    for (int i2 = 0; i2 < 4; ++i2) {
      int ra = wr * 64 + i2 * 16 + lr;
      af[i2] = *(const bf16x8*)(&As[buf][0] + ra * 32 + ((lg ^ (ra & 3)) << 3));
      int rb = wc * 64 + i2 * 16 + lr;
      bfr[i2] = *(const bf16x8*)(&Bs[buf][0] + rb * 32 + ((lg ^ (rb & 3)) << 3));
    }
#pragma unroll
    for (int i2 = 0; i2 < 4; ++i2)
#pragma unroll
      for (int j = 0; j < 4; ++j)
        acc[i2][j] = mfma16(af[i2], bfr[j], acc[i2][j]);
  };

  STAGE(0, 0);
  STAGE(1, 32);
  int cur = 0;
  for (int tt = 0; tt < 31; ++tt) {
    asm volatile("s_waitcnt vmcnt(4)" ::: "memory");  // tile tt landed; tt+1 in flight
    __builtin_amdgcn_s_barrier();
    COMPUTE(cur);
    asm volatile("s_waitcnt lgkmcnt(0)" ::: "memory");  // all reads of buf cur done
    __builtin_amdgcn_s_barrier();
    if (tt + 2 < 32) STAGE(cur, (tt + 2) * 32);
    cur ^= 1;
  }
  asm volatile("s_waitcnt vmcnt(0)" ::: "memory");  // final tile
  __builtin_amdgcn_s_barrier();
  COMPUTE(cur);

#pragma unroll
  for (int i2 = 0; i2 < 4; ++i2) {
    int row0 = m0 + wr * 64 + i2 * 16 + lg * 4;
    int bb = row0 >> 11, s0r = row0 & (SEQ - 1);
    if (seg < 2) {
      bf16* dst = (seg == 0) ? qh : kh;
      float scl = (seg == 0) ? QSCALE : 1.0f;
      size_t base = ((size_t)(bb * NH + hh) * SEQ + s0r) * HD;
#pragma unroll
      for (int j = 0; j < 2; ++j) {
        int dlo = j * 16 + lr;  // 0..31
#pragma unroll
        for (int r = 0; r < 4; ++r) {
          float2 cs = tab[(size_t)(s0r + r) * 32 + dlo];
          float a = acc[i2][j][r], b2 = acc[i2][j + 2][r];
          float na = (a * cs.x - b2 * cs.y) * scl;
          float nb = (b2 * cs.x + a * cs.y) * scl;
          dst[base + (size_t)r * HD + dlo] = (bf16)na;
          dst[base + (size_t)r * HD + dlo + 32] = (bf16)nb;
        }
      }
    } else {
#pragma unroll
      for (int j = 0; j < 4; ++j) {
        int d = j * 16 + lr;
        s16x4 pk;
#pragma unroll
        for (int r = 0; r < 4; ++r) pk[r] = __builtin_bit_cast(short, (bf16)acc[i2][j][r]);
        *(s16x4*)(vt + ((size_t)(bb * NH + hh) * HD + d) * SEQ + s0r) = pk;
      }
    }
  }
}

// C = A(MxK) * B(NxK)^T, f32 out (final projection). T1 XCD-chunked remap +
// T4 counted-vmcnt double-buffer pipeline (R19 WIN).
__global__ __launch_bounds__(256)
void gemm_bt_f32(const bf16* __restrict__ A, const bf16* __restrict__ B,
                 float* __restrict__ C, int M, int N, int K) {
  __shared__ __attribute__((aligned(16))) bf16 As[2][128 * 32];
  __shared__ __attribute__((aligned(16))) bf16 Bs[2][128 * 32];
  const int t = threadIdx.x;
  const int wv = t >> 6, ln = t & 63, lr = ln & 15, lg = ln >> 4;
  const int wr = wv >> 1, wc = wv & 1;
  const int l_hw = blockIdx.x + 8 * blockIdx.y;      // hw dispatch order
  const int lid = (l_hw & 7) * 32 + (l_hw >> 3);     // bijective (256 % 8 == 0)
  const int m0 = (lid >> 3) * 128, n0 = (lid & 7) * 128;
  const int srow = t >> 2, sslot = t & 3;

  f32x4 acc[4][4] = {};

  auto STAGE = [&](int buf, int kt) {
#pragma unroll
    for (int c = 0; c < 2; ++c) {
      int row = srow + (c << 6);
      int lsl = sslot ^ (row & 3);
      gl_lds16(A + (size_t)(m0 + row) * K + kt + lsl * 8, &As[buf][0] + c * 2048 + wv * 512);
      gl_lds16(B + (size_t)(n0 + row) * K + kt + lsl * 8, &Bs[buf][0] + c * 2048 + wv * 512);
    }
  };

  auto COMPUTE = [&](int buf) {
    bf16x8 af[4], bfr[4];
#pragma unroll
    for (int i = 0; i < 4; ++i) {
      int ra = wr * 64 + i * 16 + lr;
      af[i] = *(const bf16x8*)(&As[buf][0] + ra * 32 + ((lg ^ (ra & 3)) << 3));
      int rb = wc * 64 + i * 16 + lr;
      bfr[i] = *(const bf16x8*)(&Bs[buf][0] + rb * 32 + ((lg ^ (rb & 3)) << 3));
    }
#pragma unroll
    for (int i = 0; i < 4; ++i)
#pragma unroll
      for (int j = 0; j < 4; ++j)
        acc[i][j] = mfma16(af[i], bfr[j], acc[i][j]);
  };

  STAGE(0, 0);
  STAGE(1, 32);
  int cur = 0;
  for (int tt = 0; tt < 31; ++tt) {
    asm volatile("s_waitcnt vmcnt(4)" ::: "memory");
    __builtin_amdgcn_s_barrier();
    COMPUTE(cur);
    asm volatile("s_waitcnt lgkmcnt(0)" ::: "memory");
    __builtin_amdgcn_s_barrier();
    if (tt + 2 < 32) STAGE(cur, (tt + 2) * 32);
    cur ^= 1;
  }
  asm volatile("s_waitcnt vmcnt(0)" ::: "memory");
  __builtin_amdgcn_s_barrier();
  COMPUTE(cur);

#pragma unroll
  for (int i = 0; i < 4; ++i) {
    int row0 = m0 + wr * 64 + i * 16 + lg * 4;
#pragma unroll
    for (int j = 0; j < 4; ++j) {
      int col = n0 + wc * 64 + j * 16 + lr;
#pragma unroll
      for (int r = 0; r < 4; ++r)
        C[(size_t)(row0 + r) * N + col] = acc[i][j][r];
    }
  }
}

// ---------------- Flash attention: R7 body + T4 counted-vmcnt pipeline -----
// 1024 blocks x 256 thr (4 waves). Block = (bh, qt); LDS 40 KB -> 4 blocks/CU.
// Proven plateau config: swapped MFMAs, lane-local softmax, P via swizzled
// LDS, T13 defer-max, counted 2-deep staging pipeline (R20, best measured).
template <bool MASKED>
static __device__ __forceinline__ void attn_tile_lds(
    const bf16* Ksb, const bf16* Vsb, unsigned* plw,
    const bf16x8* qf, f32x4* acc, float& m_run, float& l_run,
    int lr, int lg, int qrow, int s0) {
  // ---- QK^T (swapped: A=K from LDS, B=q regs) ----
  f32x4 sc[4] = {};
#pragma unroll
  for (int fi = 0; fi < 4; ++fi) {
    int row = fi * 16 + lr;
    int sw = row & 7;
    bf16x8 k0 = *(const bf16x8*)(Ksb + row * 64 + ((lg ^ sw) << 3));
    bf16x8 k1 = *(const bf16x8*)(Ksb + row * 64 + (((4 + lg) ^ sw) << 3));
    sc[fi] = mfma16(k0, qf[0], sc[fi]);
    sc[fi] = mfma16(k1, qf[1], sc[fi]);
  }
  // ---- mask (diagonal tile only) ----
  if (MASKED) {
#pragma unroll
    for (int fi = 0; fi < 4; ++fi)
#pragma unroll
      for (int r = 0; r < 4; ++r) {
        int kv = s0 + fi * 16 + lg * 4 + r;
        sc[fi][r] = (kv <= qrow) ? sc[fi][r] : -3e38f;
      }
  }
  // ---- lane-local softmax (q = lr fixed per lane) ----
  float mx = fmaxf(fmaxf(vmax4(sc[0]), vmax4(sc[1])),
                   fmaxf(vmax4(sc[2]), vmax4(sc[3])));
  mx = fmaxf(mx, __shfl_xor(mx, 16));
  mx = fmaxf(mx, __shfl_xor(mx, 32));
  // T13 defer-max: only rescale when some q-row exceeds its running max.
  if (!__all(mx <= m_run)) {
    float mn = fmaxf(m_run, mx);
    float alpha = __builtin_amdgcn_exp2f(m_run - mn);
    m_run = mn;
    l_run *= alpha;
#pragma unroll
    for (int d0 = 0; d0 < 4; ++d0)
#pragma unroll
      for (int r = 0; r < 4; ++r) acc[d0][r] *= alpha;
  }
  float pf[4][4], sm = 0.0f;
#pragma unroll
  for (int fi = 0; fi < 4; ++fi)
#pragma unroll
    for (int r = 0; r < 4; ++r) {
      pf[fi][r] = __builtin_amdgcn_exp2f(sc[fi][r] - m_run);
      sm += pf[fi][r];
    }
  sm += __shfl_xor(sm, 16);
  sm += __shfl_xor(sm, 32);
  l_run += sm;

  // ---- P: (kv = fi*16+lg*4+r, q = lr) -> q-major B-fragments via LDS ----
  const int sw2 = (lr & 7) << 2;
#pragma unroll
  for (int fi = 0; fi < 4; ++fi)
#pragma unroll
    for (int hh = 0; hh < 2; ++hh)
      plw[lr * 32 + ((fi * 8 + lg * 2 + hh) ^ sw2)] =
          cvt_pk_bf16(pf[fi][2 * hh], pf[fi][2 * hh + 1]);
  asm volatile("s_waitcnt lgkmcnt(0)" ::: "memory");
  __builtin_amdgcn_sched_barrier(0);
#pragma unroll
  for (int kc = 0; kc < 2; ++kc) {
    u32x4 praw = *(const u32x4*)(plw + lr * 32 + ((kc * 16 + lg * 4) ^ sw2));
    bf16x8 pb = __builtin_bit_cast(bf16x8, praw);
#pragma unroll
    for (int d0 = 0; d0 < 4; ++d0) {
      int row = d0 * 16 + lr;
      int sw = row & 7;
      bf16x8 vf = *(const bf16x8*)(Vsb + row * 64 + (((kc * 4 + lg) ^ sw) << 3));
      acc[d0] = mfma16(vf, pb, acc[d0]);
    }
  }
  // keep later LDS writes from hoisting above this tile's reads
  asm volatile("" ::: "memory");
}

__global__ __launch_bounds__(256, 4)
void attn_k(const bf16* __restrict__ qh, const bf16* __restrict__ kh,
            const bf16* __restrict__ vt, bf16* __restrict__ ao) {
  __shared__ __attribute__((aligned(16))) bf16 Ks[2][64 * 64];    // 16 KB
  __shared__ __attribute__((aligned(16))) bf16 Vs[2][64 * 64];    // 16 KB
  __shared__ __attribute__((aligned(16))) unsigned plds[4][512];  // 8 KB

  const int t = threadIdx.x, wv = t >> 6, ln = t & 63, lr = ln & 15, lg = ln >> 4;
  // LPT + XCD-grouped: xcd = bid&7 owns 4 bh; qt descending within each XCD.
  const int bid = blockIdx.x;            // 1024 blocks
  const int xcd = bid & 7, g = bid >> 3; // g in 0..127
  const int bh = xcd * 4 + (g & 3);
  const int qt = 31 - (g >> 2);
  const int b = bh >> 4, h = bh & 15;

  const bf16* qp = qh + (size_t)bh * SEQ * HD;
  const bf16* kp = kh + (size_t)bh * SEQ * HD;
  const bf16* vp = vt + (size_t)bh * HD * SEQ;
  unsigned* plw = &plds[wv][0];

  const int qrow = qt * 64 + wv * 16 + lr;

  bf16x8 qf[2];
  qf[0] = *(const bf16x8*)(qp + (size_t)qrow * HD + lg * 8);
  qf[1] = *(const bf16x8*)(qp + (size_t)qrow * HD + 32 + lg * 8);

  f32x4 acc[4] = {};
  float m_run = -3e38f, l_run = 0.0f;

  const int nt = qt + 1;

  auto STAGE = [&](int buf, int tt) {  // 4 VMEM instructions per wave
    int s0 = tt * 64;
#pragma unroll
    for (int c = 0; c < 2; ++c) {
      int rA = wv * 16 + c * 8;            // wave-uniform 8-row chunk base
      int row = rA + (ln >> 3);
      int sl = (ln & 7) ^ (row & 7);       // pre-swizzled global source
      gl_lds16(kp + (size_t)(s0 + row) * HD + (sl << 3), &Ks[buf][rA * 64]);
      gl_lds16(vp + (size_t)row * SEQ + s0 + (sl << 3), &Vs[buf][rA * 64]);
    }
  };

  STAGE(0, 0);
  if (nt > 1) STAGE(1, 1);

  int cur = 0;
  for (int tt = 0; tt < nt; ++tt) {
    if (tt + 1 < nt)
      asm volatile("s_waitcnt vmcnt(4)" ::: "memory");  // tile tt landed; tt+1 in flight
    else
      asm volatile("s_waitcnt vmcnt(0)" ::: "memory");  // last tile: nothing beyond
    __builtin_amdgcn_s_barrier();
    if (tt == qt)
      attn_tile_lds<true>(&Ks[cur][0], &Vs[cur][0], plw, qf, acc, m_run, l_run,
                          lr, lg, qrow, tt * 64);
    else
      attn_tile_lds<false>(&Ks[cur][0], &Vs[cur][0], plw, qf, acc, m_run, l_run,
                           lr, lg, qrow, tt * 64);
    asm volatile("s_waitcnt lgkmcnt(0)" ::: "memory");  // all reads of buf cur done
    __builtin_amdgcn_s_barrier();
    if (tt + 2 < nt) STAGE(cur, tt + 2);
    cur ^= 1;
  }

  // epilogue: acc^T (d = d0*16+lg*4+r, q = lr) -> ao[b][s=qrow][h*64+d]
  float invl = 1.0f / l_run;
  bf16* aop = ao + ((size_t)b * SEQ + qrow) * DM + h * HD;
#pragma unroll
  for (int d0 = 0; d0 < 4; ++d0) {
    unsigned lo = cvt_pk_bf16(acc[d0][0] * invl, acc[d0][1] * invl);
    unsigned hi = cvt_pk_bf16(acc[d0][2] * invl, acc[d0][3] * invl);
    uint2 pk; pk.x = lo; pk.y = hi;
    *(uint2*)(aop + d0 * 16 + lg * 4) = pk;
  }
}

extern "C" void kernel_launch(void* const* d_in, const int* in_sizes, int n_in,
                              void* d_out, int out_size, void* d_ws, size_t ws_size,
                              hipStream_t stream) {
  const float* x = (const float*)d_in[0];
  const float* wq = (const float*)d_in[1];
  const float* wk = (const float*)d_in[2];
  const float* wv = (const float*)d_in[3];
  const float* wo = (const float*)d_in[4];
  // d_in[5] = attention_mask: known causal tril, handled analytically.

  char* ws = (char*)d_ws;
  const size_t MB = 1ull << 20;
  bf16* xb    = (bf16*)ws;              // 8 MB (reused as attn-out once x is dead)
  bf16* wqkvb = (bf16*)(ws + 8 * MB);   // 6 MB [3072][1024]
  bf16* wob   = (bf16*)(ws + 14 * MB);  // 2 MB
  bf16* qhb   = (bf16*)(ws + 16 * MB);  // 8 MB [b][h][s][64]
  bf16* khb   = (bf16*)(ws + 24 * MB);  // 8 MB [b][h][s][64]
  bf16* vtb   = (bf16*)(ws + 32 * MB);  // 8 MB [b][h][d][s]
  float* tab  = (float*)(ws + 40 * MB); // 512 KB float2[2048][32]
  bf16* aob = xb;

  prep_k<<<8448, 256, 0, stream>>>(x, wq, wk, wv, wo, xb, wqkvb, tab);

  gemm_qkv<<<dim3(24, 32), 256, 0, stream>>>(xb, wqkvb, qhb, khb, vtb, (const float2*)tab);

  attn_k<<<1024, 256, 0, stream>>>(qhb, khb, vtb, aob);

  gemm_bt_f32<<<dim3(8, 32), 256, 0, stream>>>(aob, wob, (float*)d_out, 4096, 1024, 1024);
}